// Round 1
// baseline (346.417 us; speedup 1.0000x reference)
//
#include <hip/hip_runtime.h>
#include <math.h>

#define CTXN 336
#define PREDN 30
#define NSAMP 100
#define BATCH 1024
#define TPAST 512
#define HID 128
#define NTF 4
#define SFK 4826          /* th(2) + 14*336 + 120 : maps to W1 rows 30..4855 */

/* ws layout in floats */
#define SF_OFF 0
#define SF_ELEMS (BATCH*SFK)
#define LS_OFF (SF_OFF + SF_ELEMS)           /* loc[b] at LS_OFF+b, scale[b] at LS_OFF+1024+b */
#define KC 8
#define PART_OFF (LS_OFF + 2*BATCH)
#define PART_ELEMS (KC*BATCH*HID)
#define BASE_OFF (PART_OFF + PART_ELEMS)
#define KCHUNK 604                            /* 8*604 = 4832 >= 4826 */

__device__ inline unsigned rotl32(unsigned x, unsigned d){ return (x<<d)|(x>>(32u-d)); }

__device__ inline void tf2x32(unsigned k0, unsigned k1, unsigned x0, unsigned x1,
                              unsigned &o0, unsigned &o1){
  unsigned k2 = k0 ^ k1 ^ 0x1BD11BDAu;
  x0 += k0; x1 += k1;
  x0+=x1; x1=rotl32(x1,13); x1^=x0;
  x0+=x1; x1=rotl32(x1,15); x1^=x0;
  x0+=x1; x1=rotl32(x1,26); x1^=x0;
  x0+=x1; x1=rotl32(x1, 6); x1^=x0;
  x0+=k1; x1+=k2+1u;
  x0+=x1; x1=rotl32(x1,17); x1^=x0;
  x0+=x1; x1=rotl32(x1,29); x1^=x0;
  x0+=x1; x1=rotl32(x1,16); x1^=x0;
  x0+=x1; x1=rotl32(x1,24); x1^=x0;
  x0+=k2; x1+=k0+2u;
  x0+=x1; x1=rotl32(x1,13); x1^=x0;
  x0+=x1; x1=rotl32(x1,15); x1^=x0;
  x0+=x1; x1=rotl32(x1,26); x1^=x0;
  x0+=x1; x1=rotl32(x1, 6); x1^=x0;
  x0+=k0; x1+=k1+3u;
  x0+=x1; x1=rotl32(x1,17); x1^=x0;
  x0+=x1; x1=rotl32(x1,29); x1^=x0;
  x0+=x1; x1=rotl32(x1,16); x1^=x0;
  x0+=x1; x1=rotl32(x1,24); x1^=x0;
  x0+=k1; x1+=k2+4u;
  x0+=x1; x1=rotl32(x1,13); x1^=x0;
  x0+=x1; x1=rotl32(x1,15); x1^=x0;
  x0+=x1; x1=rotl32(x1,26); x1^=x0;
  x0+=x1; x1=rotl32(x1, 6); x1^=x0;
  x0+=k2; x1+=k0+5u;
  o0=x0; o1=x1;
}

/* XLA ErfInv32 (Giles) polynomial */
__device__ inline float erfinv_f32(float x){
  float w = -log1pf(-x*x);
  float p;
  if (w < 5.0f) {
    w -= 2.5f;
    p = 2.81022636e-08f;
    p = fmaf(p, w, 3.43273939e-07f);
    p = fmaf(p, w, -3.5233877e-06f);
    p = fmaf(p, w, -4.39150654e-06f);
    p = fmaf(p, w, 0.00021858087f);
    p = fmaf(p, w, -0.00125372503f);
    p = fmaf(p, w, -0.00417768164f);
    p = fmaf(p, w, 0.246640727f);
    p = fmaf(p, w, 1.50140941f);
  } else {
    w = sqrtf(w) - 3.0f;
    p = -0.000200214257f;
    p = fmaf(p, w, 0.000100950558f);
    p = fmaf(p, w, 0.00134934322f);
    p = fmaf(p, w, -0.00367342844f);
    p = fmaf(p, w, 0.00573950773f);
    p = fmaf(p, w, -0.0076224613f);
    p = fmaf(p, w, 0.00943887047f);
    p = fmaf(p, w, 1.00167406f);
    p = fmaf(p, w, 2.83297682f);
  }
  return p*x;
}

/* jax.random.normal element j of flat (100,1024,30) array, key(42), partitionable stream */
__device__ inline float jax_normal(unsigned j){
  unsigned o0,o1; tf2x32(0u,42u,0u,j,o0,o1);
  unsigned bits = o0 ^ o1;
  float f = __uint_as_float((bits>>9)|0x3f800000u) - 1.0f;
  const float LO = -0.99999994f;
  float u = f*2.0f + LO;
  u = fmaxf(LO, u);
  return 1.41421356f * erfinv_f32(u);
}

__device__ inline float gelu_tanh(float x){
  float x3 = x*x*x;
  return 0.5f*x*(1.0f + tanhf(0.79788452f*(x + 0.044715f*x3)));
}

__device__ inline float blockReduceSum256(float v, volatile float* red){
  for (int o=32;o>0;o>>=1) v += __shfl_down(v, o, 64);
  int w = threadIdx.x>>6, lane = threadIdx.x&63;
  __syncthreads();                 /* protect red from previous use */
  if (lane==0) red[w]=v;
  __syncthreads();
  return red[0]+red[1]+red[2]+red[3];
}

/* ---------------- Kernel A: per-row features ---------------- */
__global__ __launch_bounds__(256) void feat_kernel(
    const float* __restrict__ pt, const float* __restrict__ ptf,
    const float* __restrict__ ftf, float* __restrict__ ws)
{
  const int b = blockIdx.x;
  const int tid = threadIdx.x;
  __shared__ float seg[343];       /* pt[b][169..511]; ctx[t]=seg[7+t] */
  __shared__ float dbuf[CTXN];
  __shared__ float rbuf[CTXN];
  __shared__ float red[4];
  __shared__ float med[2];

  for (int i = tid; i < 343; i += 256) seg[i] = pt[(size_t)b*TPAST + 169 + i];
  if (tid < 2) med[tid] = 0.f;
  __syncthreads();

  /* median: rank-counting over 336 elements */
  for (int t = tid; t < CTXN; t += 256) {
    float v = seg[7+t];
    int clt=0, ceq=0;
    for (int s2=0;s2<CTXN;s2++){ float w = seg[7+s2]; clt += (w < v); ceq += (w == v); }
    if (clt <= 167 && 167 < clt+ceq) med[0] = v;
    if (clt <= 168 && 168 < clt+ceq) med[1] = v;
  }
  __syncthreads();
  float loc = 0.5f*(med[0]+med[1]);

  float part = 0.f;
  for (int t=tid;t<CTXN;t+=256) part += fabsf(seg[7+t]-loc);
  part = blockReduceSum256(part, red);
  float scale = fmaxf(part/(float)CTXN, 1e-6f);

  float pd = 0.f;
  for (int t=tid;t<CTXN;t+=256){
    float d = (t==0)?0.f:(seg[7+t]-seg[6+t]);
    dbuf[t]=d; pd += fabsf(d);
  }
  pd = blockReduceSum256(pd, red);
  float dden = fmaxf(pd/(float)CTXN, 1e-6f);

  float pr = 0.f;
  for (int t=tid;t<CTXN;t+=256){
    int a = t-4; if (a<0) a=0;
    int n = t+1-a;
    float s=0.f, s2s=0.f;
    for (int jj=a;jj<=t;jj++){ float v=seg[7+jj]; s+=v; s2s+=v*v; }
    float fn = (float)n;
    float var = (s2s - s*s/fn) / fmaxf(fn-1.f, 1.f);
    float r = (t>=2)? sqrtf(fmaxf(var,1e-12f)) : 0.f;
    rbuf[t]=r; pr += r;
  }
  pr = blockReduceSum256(pr, red);
  float rden = fmaxf(pr/(float)CTXN, 1e-6f);
  __syncthreads();

  float* sf = ws + SF_OFF + (size_t)b*SFK;
  if (tid<2) sf[tid]=1.0f;         /* th */
  for (int t=tid;t<CTXN;t+=256){
    #pragma unroll
    for (int c=0;c<8;c++)          /* lag channel c uses pt[176-c+t] = seg[7-c+t] */
      sf[2 + c*CTXN + t] = (seg[7 - c + t] - loc)/scale;
    sf[2+8*CTXN+t] = dbuf[t]/dden;
    sf[2+9*CTXN+t] = rbuf[t]/rden;
    #pragma unroll
    for (int f=0; f<4; f++)
      sf[2 + (10+f)*CTXN + t] = ptf[(size_t)b*TPAST*NTF + (size_t)(176+t)*NTF + f];
  }
  for (int i=tid;i<NTF*PREDN;i+=256){
    int f = i/PREDN, t = i - f*PREDN;
    sf[2+14*CTXN + i] = ftf[(size_t)b*PREDN*NTF + t*NTF + f];
  }
  if (tid==0){ ws[LS_OFF + b] = loc; ws[LS_OFF + BATCH + b] = scale; }
}

/* ---------------- Kernel B: split-K partial base GEMM ---------------- */
__global__ __launch_bounds__(256) void base_partial_kernel(
    const float* __restrict__ W1, const float* __restrict__ sf, float* __restrict__ partb)
{
  const int h  = threadIdx.x & 127;
  const int rh = threadIdx.x >> 7;
  const int r0 = blockIdx.x*8 + rh*4;
  const int kc = blockIdx.y;
  const int kbeg = kc*KCHUNK;
  const int kend = min(SFK, kbeg+KCHUNK);
  float acc0=0.f,acc1=0.f,acc2=0.f,acc3=0.f;
  const float* sf0 = sf + (size_t)r0*SFK;
  for (int k=kbeg;k<kend;k++){
    float w = W1[(size_t)(30+k)*HID + h];
    acc0 = fmaf(sf0[k], w, acc0);
    acc1 = fmaf(sf0[SFK + k], w, acc1);
    acc2 = fmaf(sf0[2*(size_t)SFK + k], w, acc2);
    acc3 = fmaf(sf0[3*(size_t)SFK + k], w, acc3);
  }
  float* p = partb + (size_t)kc*BATCH*HID + (size_t)r0*HID + h;
  p[0]=acc0; p[HID]=acc1; p[2*HID]=acc2; p[3*HID]=acc3;
}

__global__ __launch_bounds__(256) void base_reduce_kernel(
    const float* __restrict__ partb, const float* __restrict__ b1, float* __restrict__ base)
{
  int i = blockIdx.x*256 + threadIdx.x;  /* 0..131071 */
  int h = i & 127;
  float s = b1[h];
  #pragma unroll
  for (int kc=0;kc<KC;kc++) s += partb[(size_t)kc*BATCH*HID + i];
  base[i] = s;
}

/* ---------------- Kernel D: 100-sample MLP ---------------- */
__global__ __launch_bounds__(256) void mlp_kernel(
    const float* __restrict__ W1, const float* __restrict__ W2, const float* __restrict__ b2,
    const float* __restrict__ W3, const float* __restrict__ b3,
    const float* __restrict__ ws, float* __restrict__ out)
{
  const int s  = blockIdx.y;
  const int b0 = blockIdx.x*32;
  const int tid = threadIdx.x;
  __shared__ float zt[32][PREDN];
  __shared__ float h1s[32][HID];
  __shared__ float h2s[32][HID];
  const float* base = ws + BASE_OFF;

  for (int i=tid;i<32*PREDN;i+=256){
    int r = i/PREDN, t = i - r*PREDN;
    unsigned j = (unsigned)(s*30720 + (b0+r)*30 + t);
    zt[r][t] = jax_normal(j);
  }
  __syncthreads();

  const int h = tid & 127; const int g = tid >> 7;
  float w1r[PREDN];
  #pragma unroll
  for (int t=0;t<PREDN;t++) w1r[t] = W1[t*HID + h];
  for (int rr=0; rr<16; rr++){
    int r = g*16 + rr;
    float acc = base[(size_t)(b0+r)*HID + h];
    #pragma unroll
    for (int t=0;t<PREDN;t++) acc = fmaf(zt[r][t], w1r[t], acc);
    h1s[r][h] = gelu_tanh(acc);
  }
  __syncthreads();

  float acc2[16];
  #pragma unroll
  for (int rr=0;rr<16;rr++) acc2[rr]=0.f;
  for (int k=0;k<HID;k++){
    float w = W2[k*HID + h];
    #pragma unroll
    for (int rr=0;rr<16;rr++) acc2[rr] = fmaf(h1s[g*16+rr][k], w, acc2[rr]);
  }
  float bb = b2[h];
  #pragma unroll
  for (int rr=0;rr<16;rr++) h2s[g*16+rr][h] = gelu_tanh(acc2[rr]+bb);
  __syncthreads();

  if (tid < 240){
    int t  = tid % PREDN;
    int rg = tid / PREDN;      /* 0..7, rows rg*4..rg*4+3 */
    float b3t = b3[t];
    float acc[4];
    #pragma unroll
    for (int q=0;q<4;q++) acc[q]=b3t;
    for (int k=0;k<HID;k++){
      float w = W3[k*PREDN + t];
      #pragma unroll
      for (int q=0;q<4;q++) acc[q] = fmaf(h2s[rg*4+q][k], w, acc[q]);
    }
    #pragma unroll
    for (int q=0;q<4;q++){
      int r = rg*4+q;
      int gb = b0 + r;
      float loc = ws[LS_OFF + gb];
      float scl = ws[LS_OFF + BATCH + gb];
      out[(size_t)gb*(NSAMP*PREDN) + s*PREDN + t] = (zt[r][t] - acc[q])*scl + loc;
    }
  }
}

extern "C" void kernel_launch(void* const* d_in, const int* in_sizes, int n_in,
                              void* d_out, int out_size, void* d_ws, size_t ws_size,
                              hipStream_t stream) {
  (void)in_sizes; (void)n_in; (void)out_size; (void)ws_size;
  const float* pt  = (const float*)d_in[0];
  const float* ptf = (const float*)d_in[2];
  const float* ftf = (const float*)d_in[3];
  const float* W1  = (const float*)d_in[4];
  const float* b1  = (const float*)d_in[5];
  const float* W2  = (const float*)d_in[6];
  const float* b2  = (const float*)d_in[7];
  const float* W3  = (const float*)d_in[8];
  const float* b3  = (const float*)d_in[9];
  float* out = (float*)d_out;
  float* ws  = (float*)d_ws;

  hipLaunchKernelGGL(feat_kernel, dim3(BATCH), dim3(256), 0, stream, pt, ptf, ftf, ws);
  hipLaunchKernelGGL(base_partial_kernel, dim3(BATCH/8, KC), dim3(256), 0, stream,
                     W1, ws + SF_OFF, ws + PART_OFF);
  hipLaunchKernelGGL(base_reduce_kernel, dim3(BATCH*HID/256), dim3(256), 0, stream,
                     ws + PART_OFF, b1, ws + BASE_OFF);
  hipLaunchKernelGGL(mlp_kernel, dim3(BATCH/32, NSAMP), dim3(256), 0, stream,
                     W1, W2, b2, W3, b3, ws, out);
}

// Round 2
// 189.020 us; speedup vs baseline: 1.8327x; 1.8327x over previous
//
#include <hip/hip_runtime.h>
#include <math.h>

#define CTXN 336
#define PREDN 30
#define NSAMP 100
#define BATCH 1024
#define TPAST 512
#define HID 128
#define NTF 4
#define SFK 4826          /* th(2) + 14*336 + 120 : maps to W1 rows 30..4855 */
#define SFKP 4832         /* padded to multiple of 32; pad region zeroed */

/* ws layout in floats */
#define SF_OFF 0
#define SF_ELEMS (BATCH*SFKP)
#define LS_OFF (SF_OFF + SF_ELEMS)           /* loc[b] at LS_OFF+b, scale[b] at LS_OFF+1024+b */
#define KC 8
#define PART_OFF (LS_OFF + 2*BATCH)
#define PART_ELEMS (KC*BATCH*HID)
#define BASE_OFF (PART_OFF + PART_ELEMS)
#define KCH 608                               /* 7 chunks of 608 + last 576; all %32==0 */

__device__ inline unsigned rotl32(unsigned x, unsigned d){ return (x<<d)|(x>>(32u-d)); }

__device__ inline void tf2x32(unsigned k0, unsigned k1, unsigned x0, unsigned x1,
                              unsigned &o0, unsigned &o1){
  unsigned k2 = k0 ^ k1 ^ 0x1BD11BDAu;
  x0 += k0; x1 += k1;
  x0+=x1; x1=rotl32(x1,13); x1^=x0;
  x0+=x1; x1=rotl32(x1,15); x1^=x0;
  x0+=x1; x1=rotl32(x1,26); x1^=x0;
  x0+=x1; x1=rotl32(x1, 6); x1^=x0;
  x0+=k1; x1+=k2+1u;
  x0+=x1; x1=rotl32(x1,17); x1^=x0;
  x0+=x1; x1=rotl32(x1,29); x1^=x0;
  x0+=x1; x1=rotl32(x1,16); x1^=x0;
  x0+=x1; x1=rotl32(x1,24); x1^=x0;
  x0+=k2; x1+=k0+2u;
  x0+=x1; x1=rotl32(x1,13); x1^=x0;
  x0+=x1; x1=rotl32(x1,15); x1^=x0;
  x0+=x1; x1=rotl32(x1,26); x1^=x0;
  x0+=x1; x1=rotl32(x1, 6); x1^=x0;
  x0+=k0; x1+=k1+3u;
  x0+=x1; x1=rotl32(x1,17); x1^=x0;
  x0+=x1; x1=rotl32(x1,29); x1^=x0;
  x0+=x1; x1=rotl32(x1,16); x1^=x0;
  x0+=x1; x1=rotl32(x1,24); x1^=x0;
  x0+=k1; x1+=k2+4u;
  x0+=x1; x1=rotl32(x1,13); x1^=x0;
  x0+=x1; x1=rotl32(x1,15); x1^=x0;
  x0+=x1; x1=rotl32(x1,26); x1^=x0;
  x0+=x1; x1=rotl32(x1, 6); x1^=x0;
  x0+=k2; x1+=k0+5u;
  o0=x0; o1=x1;
}

/* XLA ErfInv32 (Giles) polynomial */
__device__ inline float erfinv_f32(float x){
  float w = -log1pf(-x*x);
  float p;
  if (w < 5.0f) {
    w -= 2.5f;
    p = 2.81022636e-08f;
    p = fmaf(p, w, 3.43273939e-07f);
    p = fmaf(p, w, -3.5233877e-06f);
    p = fmaf(p, w, -4.39150654e-06f);
    p = fmaf(p, w, 0.00021858087f);
    p = fmaf(p, w, -0.00125372503f);
    p = fmaf(p, w, -0.00417768164f);
    p = fmaf(p, w, 0.246640727f);
    p = fmaf(p, w, 1.50140941f);
  } else {
    w = sqrtf(w) - 3.0f;
    p = -0.000200214257f;
    p = fmaf(p, w, 0.000100950558f);
    p = fmaf(p, w, 0.00134934322f);
    p = fmaf(p, w, -0.00367342844f);
    p = fmaf(p, w, 0.00573950773f);
    p = fmaf(p, w, -0.0076224613f);
    p = fmaf(p, w, 0.00943887047f);
    p = fmaf(p, w, 1.00167406f);
    p = fmaf(p, w, 2.83297682f);
  }
  return p*x;
}

/* jax.random.normal element j of flat (100,1024,30) array, key(42), partitionable stream */
__device__ inline float jax_normal(unsigned j){
  unsigned o0,o1; tf2x32(0u,42u,0u,j,o0,o1);
  unsigned bits = o0 ^ o1;
  float f = __uint_as_float((bits>>9)|0x3f800000u) - 1.0f;
  const float LO = -0.99999994f;
  float u = f*2.0f + LO;
  u = fmaxf(LO, u);
  return 1.41421356f * erfinv_f32(u);
}

__device__ inline float gelu_tanh(float x){
  float x3 = x*x*x;
  return 0.5f*x*(1.0f + tanhf(0.79788452f*(x + 0.044715f*x3)));
}

__device__ inline float blockReduceSum256(float v, volatile float* red){
  for (int o=32;o>0;o>>=1) v += __shfl_down(v, o, 64);
  int w = threadIdx.x>>6, lane = threadIdx.x&63;
  __syncthreads();                 /* protect red from previous use */
  if (lane==0) red[w]=v;
  __syncthreads();
  return red[0]+red[1]+red[2]+red[3];
}

/* ---------------- Kernel A: per-row features ---------------- */
__global__ __launch_bounds__(256) void feat_kernel(
    const float* __restrict__ pt, const float* __restrict__ ptf,
    const float* __restrict__ ftf, float* __restrict__ ws)
{
  const int b = blockIdx.x;
  const int tid = threadIdx.x;
  __shared__ float seg[343];       /* pt[b][169..511]; ctx[t]=seg[7+t] */
  __shared__ float dbuf[CTXN];
  __shared__ float rbuf[CTXN];
  __shared__ float red[4];
  __shared__ float med[2];

  for (int i = tid; i < 343; i += 256) seg[i] = pt[(size_t)b*TPAST + 169 + i];
  if (tid < 2) med[tid] = 0.f;
  __syncthreads();

  /* median: rank-counting over 336 elements */
  for (int t = tid; t < CTXN; t += 256) {
    float v = seg[7+t];
    int clt=0, ceq=0;
    for (int s2=0;s2<CTXN;s2++){ float w = seg[7+s2]; clt += (w < v); ceq += (w == v); }
    if (clt <= 167 && 167 < clt+ceq) med[0] = v;
    if (clt <= 168 && 168 < clt+ceq) med[1] = v;
  }
  __syncthreads();
  float loc = 0.5f*(med[0]+med[1]);

  float part = 0.f;
  for (int t=tid;t<CTXN;t+=256) part += fabsf(seg[7+t]-loc);
  part = blockReduceSum256(part, red);
  float scale = fmaxf(part/(float)CTXN, 1e-6f);

  float pd = 0.f;
  for (int t=tid;t<CTXN;t+=256){
    float d = (t==0)?0.f:(seg[7+t]-seg[6+t]);
    dbuf[t]=d; pd += fabsf(d);
  }
  pd = blockReduceSum256(pd, red);
  float dden = fmaxf(pd/(float)CTXN, 1e-6f);

  float pr = 0.f;
  for (int t=tid;t<CTXN;t+=256){
    int a = t-4; if (a<0) a=0;
    int n = t+1-a;
    float s=0.f, s2s=0.f;
    for (int jj=a;jj<=t;jj++){ float v=seg[7+jj]; s+=v; s2s+=v*v; }
    float fn = (float)n;
    float var = (s2s - s*s/fn) / fmaxf(fn-1.f, 1.f);
    float r = (t>=2)? sqrtf(fmaxf(var,1e-12f)) : 0.f;
    rbuf[t]=r; pr += r;
  }
  pr = blockReduceSum256(pr, red);
  float rden = fmaxf(pr/(float)CTXN, 1e-6f);
  __syncthreads();

  float* sf = ws + SF_OFF + (size_t)b*SFKP;
  if (tid<2) sf[tid]=1.0f;         /* th */
  if (tid<SFKP-SFK) sf[SFK+tid]=0.f;   /* zero pad */
  for (int t=tid;t<CTXN;t+=256){
    #pragma unroll
    for (int c=0;c<8;c++)          /* lag channel c uses pt[176-c+t] = seg[7-c+t] */
      sf[2 + c*CTXN + t] = (seg[7 - c + t] - loc)/scale;
    sf[2+8*CTXN+t] = dbuf[t]/dden;
    sf[2+9*CTXN+t] = rbuf[t]/rden;
    #pragma unroll
    for (int f=0; f<4; f++)
      sf[2 + (10+f)*CTXN + t] = ptf[(size_t)b*TPAST*NTF + (size_t)(176+t)*NTF + f];
  }
  for (int i=tid;i<NTF*PREDN;i+=256){
    int f = i/PREDN, t = i - f*PREDN;
    sf[2+14*CTXN + i] = ftf[(size_t)b*PREDN*NTF + t*NTF + f];
  }
  if (tid==0){ ws[LS_OFF + b] = loc; ws[LS_OFF + BATCH + b] = scale; }
}

/* ---------------- Kernel B: LDS-tiled split-K base GEMM ----------------
   block = 32 rows x 128 cols, thread tile 4x4, K chunked by 32.        */
__global__ __launch_bounds__(256) void base_partial_kernel(
    const float* __restrict__ W1, const float* __restrict__ sf, float* __restrict__ partb)
{
  __shared__ float sfT[32][32];    /* [kk][row] */
  __shared__ float wT[32][HID];    /* [kk][h]   */
  const int tid  = threadIdx.x;
  const int rowg = tid >> 5;       /* 0..7  -> rows rowg*4..+3 */
  const int colg = tid & 31;       /* 0..31 -> cols colg*4..+3 */
  const int r0 = rowg*4, c0 = colg*4;
  const int rb = blockIdx.x*32;
  const int kc = blockIdx.y;
  const int kbeg = kc*KCH;
  const int kend = (kc==KC-1) ? SFKP : (kbeg+KCH);

  float acc[4][4];
  #pragma unroll
  for (int i=0;i<4;i++)
    #pragma unroll
    for (int j=0;j<4;j++) acc[i][j]=0.f;

  const int sr  = tid >> 3;        /* 0..31 staging row */
  const int sk4 = (tid & 7) * 4;   /* 0,4,..,28 */

  for (int kk0 = kbeg; kk0 < kend; kk0 += 32) {
    float4 v = *(const float4*)(sf + (size_t)(rb + sr)*SFKP + kk0 + sk4);
    sfT[sk4+0][sr] = v.x; sfT[sk4+1][sr] = v.y;
    sfT[sk4+2][sr] = v.z; sfT[sk4+3][sr] = v.w;
    #pragma unroll
    for (int p = 0; p < 4; p++) {
      int idx = p*256 + tid;       /* 0..1023 float4 slots */
      int kk = idx >> 5;
      int h4 = (idx & 31) * 4;
      int row = 30 + kk0 + kk; if (row > 4855) row = 4855;  /* pad rows: sf=0 */
      *(float4*)&wT[kk][h4] = *(const float4*)(W1 + (size_t)row*HID + h4);
    }
    __syncthreads();
    #pragma unroll
    for (int kk = 0; kk < 32; kk++) {
      float4 a = *(const float4*)&sfT[kk][r0];
      float4 b = *(const float4*)&wT[kk][c0];
      acc[0][0]=fmaf(a.x,b.x,acc[0][0]); acc[0][1]=fmaf(a.x,b.y,acc[0][1]);
      acc[0][2]=fmaf(a.x,b.z,acc[0][2]); acc[0][3]=fmaf(a.x,b.w,acc[0][3]);
      acc[1][0]=fmaf(a.y,b.x,acc[1][0]); acc[1][1]=fmaf(a.y,b.y,acc[1][1]);
      acc[1][2]=fmaf(a.y,b.z,acc[1][2]); acc[1][3]=fmaf(a.y,b.w,acc[1][3]);
      acc[2][0]=fmaf(a.z,b.x,acc[2][0]); acc[2][1]=fmaf(a.z,b.y,acc[2][1]);
      acc[2][2]=fmaf(a.z,b.z,acc[2][2]); acc[2][3]=fmaf(a.z,b.w,acc[2][3]);
      acc[3][0]=fmaf(a.w,b.x,acc[3][0]); acc[3][1]=fmaf(a.w,b.y,acc[3][1]);
      acc[3][2]=fmaf(a.w,b.z,acc[3][2]); acc[3][3]=fmaf(a.w,b.w,acc[3][3]);
    }
    __syncthreads();
  }

  float* p = partb + (size_t)kc*BATCH*HID + (size_t)(rb + r0)*HID + c0;
  #pragma unroll
  for (int i=0;i<4;i++){
    float4 o; o.x=acc[i][0]; o.y=acc[i][1]; o.z=acc[i][2]; o.w=acc[i][3];
    *(float4*)(p + (size_t)i*HID) = o;
  }
}

__global__ __launch_bounds__(256) void base_reduce_kernel(
    const float* __restrict__ partb, const float* __restrict__ b1, float* __restrict__ base)
{
  int i = blockIdx.x*256 + threadIdx.x;  /* 0..131071 */
  int h = i & 127;
  float s = b1[h];
  #pragma unroll
  for (int kc=0;kc<KC;kc++) s += partb[(size_t)kc*BATCH*HID + i];
  base[i] = s;
}

/* ---------------- Kernel D: 100-sample MLP ---------------- */
__global__ __launch_bounds__(256) void mlp_kernel(
    const float* __restrict__ W1, const float* __restrict__ W2, const float* __restrict__ b2,
    const float* __restrict__ W3, const float* __restrict__ b3,
    const float* __restrict__ ws, float* __restrict__ out)
{
  const int s  = blockIdx.y;
  const int b0 = blockIdx.x*32;
  const int tid = threadIdx.x;
  __shared__ float zt[32][PREDN];
  __shared__ float h1s[32][HID];
  __shared__ float h2s[32][HID];
  const float* base = ws + BASE_OFF;

  for (int i=tid;i<32*PREDN;i+=256){
    int r = i/PREDN, t = i - r*PREDN;
    unsigned j = (unsigned)(s*30720 + (b0+r)*30 + t);
    zt[r][t] = jax_normal(j);
  }
  __syncthreads();

  const int h = tid & 127; const int g = tid >> 7;
  float w1r[PREDN];
  #pragma unroll
  for (int t=0;t<PREDN;t++) w1r[t] = W1[t*HID + h];
  for (int rr=0; rr<16; rr++){
    int r = g*16 + rr;
    float acc = base[(size_t)(b0+r)*HID + h];
    #pragma unroll
    for (int t=0;t<PREDN;t++) acc = fmaf(zt[r][t], w1r[t], acc);
    h1s[r][h] = gelu_tanh(acc);
  }
  __syncthreads();

  float acc2[16];
  #pragma unroll
  for (int rr=0;rr<16;rr++) acc2[rr]=0.f;
  for (int k=0;k<HID;k++){
    float w = W2[k*HID + h];
    #pragma unroll
    for (int rr=0;rr<16;rr++) acc2[rr] = fmaf(h1s[g*16+rr][k], w, acc2[rr]);
  }
  float bb = b2[h];
  #pragma unroll
  for (int rr=0;rr<16;rr++) h2s[g*16+rr][h] = gelu_tanh(acc2[rr]+bb);
  __syncthreads();

  if (tid < 240){
    int t  = tid % PREDN;
    int rg = tid / PREDN;      /* 0..7, rows rg*4..rg*4+3 */
    float b3t = b3[t];
    float acc[4];
    #pragma unroll
    for (int q=0;q<4;q++) acc[q]=b3t;
    for (int k=0;k<HID;k++){
      float w = W3[k*PREDN + t];
      #pragma unroll
      for (int q=0;q<4;q++) acc[q] = fmaf(h2s[rg*4+q][k], w, acc[q]);
    }
    #pragma unroll
    for (int q=0;q<4;q++){
      int r = rg*4+q;
      int gb = b0 + r;
      float loc = ws[LS_OFF + gb];
      float scl = ws[LS_OFF + BATCH + gb];
      out[(size_t)gb*(NSAMP*PREDN) + s*PREDN + t] = (zt[r][t] - acc[q])*scl + loc;
    }
  }
}

extern "C" void kernel_launch(void* const* d_in, const int* in_sizes, int n_in,
                              void* d_out, int out_size, void* d_ws, size_t ws_size,
                              hipStream_t stream) {
  (void)in_sizes; (void)n_in; (void)out_size; (void)ws_size;
  const float* pt  = (const float*)d_in[0];
  const float* ptf = (const float*)d_in[2];
  const float* ftf = (const float*)d_in[3];
  const float* W1  = (const float*)d_in[4];
  const float* b1  = (const float*)d_in[5];
  const float* W2  = (const float*)d_in[6];
  const float* b2  = (const float*)d_in[7];
  const float* W3  = (const float*)d_in[8];
  const float* b3  = (const float*)d_in[9];
  float* out = (float*)d_out;
  float* ws  = (float*)d_ws;

  hipLaunchKernelGGL(feat_kernel, dim3(BATCH), dim3(256), 0, stream, pt, ptf, ftf, ws);
  hipLaunchKernelGGL(base_partial_kernel, dim3(BATCH/32, KC), dim3(256), 0, stream,
                     W1, ws + SF_OFF, ws + PART_OFF);
  hipLaunchKernelGGL(base_reduce_kernel, dim3(BATCH*HID/256), dim3(256), 0, stream,
                     ws + PART_OFF, b1, ws + BASE_OFF);
  hipLaunchKernelGGL(mlp_kernel, dim3(BATCH/32, NSAMP), dim3(256), 0, stream,
                     W1, W2, b2, W3, b3, ws, out);
}

// Round 3
// 117.080 us; speedup vs baseline: 2.9588x; 1.6144x over previous
//
#include <hip/hip_runtime.h>
#include <math.h>

#define CTXN 336
#define PREDN 30
#define NSAMP 100
#define BATCH 1024
#define TPAST 512
#define HID 128
#define NTF 4
#define SFK 4826          /* th(2) + 14*336 + 120 : maps to W1 rows 30..4855 */
#define SFKP 4832         /* padded to multiple of 32; pad region zeroed */

/* ws layout in floats */
#define SF_OFF 0
#define SF_ELEMS (BATCH*SFKP)
#define LS_OFF (SF_OFF + SF_ELEMS)           /* loc[b] at LS_OFF+b, scale[b] at LS_OFF+1024+b */
#define KC 8
#define PART_OFF (LS_OFF + 2*BATCH)
#define PART_ELEMS (KC*BATCH*HID)
#define BASE_OFF (PART_OFF + PART_ELEMS)
#define KCH 608                               /* 7 chunks of 608 + last 576; all %32==0 */
#define WPREP_OFF (BASE_OFF + BATCH*HID)      /* 24576 ushorts = 12288 floats */
/* wb ushort layout: w1zb [0,4096): col*32+k ; w2b [4096,20480): col*128+k ;
   w3b [20480,24576): col*128+k (cols>=30 zero) */

typedef unsigned short ush;
typedef __attribute__((ext_vector_type(8))) short bf16x8;
typedef __attribute__((ext_vector_type(4))) float f32x4;

__device__ inline unsigned rotl32(unsigned x, unsigned d){ return (x<<d)|(x>>(32u-d)); }

__device__ inline void tf2x32(unsigned k0, unsigned k1, unsigned x0, unsigned x1,
                              unsigned &o0, unsigned &o1){
  unsigned k2 = k0 ^ k1 ^ 0x1BD11BDAu;
  x0 += k0; x1 += k1;
  x0+=x1; x1=rotl32(x1,13); x1^=x0;
  x0+=x1; x1=rotl32(x1,15); x1^=x0;
  x0+=x1; x1=rotl32(x1,26); x1^=x0;
  x0+=x1; x1=rotl32(x1, 6); x1^=x0;
  x0+=k1; x1+=k2+1u;
  x0+=x1; x1=rotl32(x1,17); x1^=x0;
  x0+=x1; x1=rotl32(x1,29); x1^=x0;
  x0+=x1; x1=rotl32(x1,16); x1^=x0;
  x0+=x1; x1=rotl32(x1,24); x1^=x0;
  x0+=k2; x1+=k0+2u;
  x0+=x1; x1=rotl32(x1,13); x1^=x0;
  x0+=x1; x1=rotl32(x1,15); x1^=x0;
  x0+=x1; x1=rotl32(x1,26); x1^=x0;
  x0+=x1; x1=rotl32(x1, 6); x1^=x0;
  x0+=k0; x1+=k1+3u;
  x0+=x1; x1=rotl32(x1,17); x1^=x0;
  x0+=x1; x1=rotl32(x1,29); x1^=x0;
  x0+=x1; x1=rotl32(x1,16); x1^=x0;
  x0+=x1; x1=rotl32(x1,24); x1^=x0;
  x0+=k1; x1+=k2+4u;
  x0+=x1; x1=rotl32(x1,13); x1^=x0;
  x0+=x1; x1=rotl32(x1,15); x1^=x0;
  x0+=x1; x1=rotl32(x1,26); x1^=x0;
  x0+=x1; x1=rotl32(x1, 6); x1^=x0;
  x0+=k2; x1+=k0+5u;
  o0=x0; o1=x1;
}

/* XLA ErfInv32 (Giles) polynomial */
__device__ inline float erfinv_f32(float x){
  float w = -log1pf(-x*x);
  float p;
  if (w < 5.0f) {
    w -= 2.5f;
    p = 2.81022636e-08f;
    p = fmaf(p, w, 3.43273939e-07f);
    p = fmaf(p, w, -3.5233877e-06f);
    p = fmaf(p, w, -4.39150654e-06f);
    p = fmaf(p, w, 0.00021858087f);
    p = fmaf(p, w, -0.00125372503f);
    p = fmaf(p, w, -0.00417768164f);
    p = fmaf(p, w, 0.246640727f);
    p = fmaf(p, w, 1.50140941f);
  } else {
    w = sqrtf(w) - 3.0f;
    p = -0.000200214257f;
    p = fmaf(p, w, 0.000100950558f);
    p = fmaf(p, w, 0.00134934322f);
    p = fmaf(p, w, -0.00367342844f);
    p = fmaf(p, w, 0.00573950773f);
    p = fmaf(p, w, -0.0076224613f);
    p = fmaf(p, w, 0.00943887047f);
    p = fmaf(p, w, 1.00167406f);
    p = fmaf(p, w, 2.83297682f);
  }
  return p*x;
}

/* jax.random.normal element j of flat (100,1024,30) array, key(42), partitionable stream */
__device__ inline float jax_normal(unsigned j){
  unsigned o0,o1; tf2x32(0u,42u,0u,j,o0,o1);
  unsigned bits = o0 ^ o1;
  float f = __uint_as_float((bits>>9)|0x3f800000u) - 1.0f;
  const float LO = -0.99999994f;
  float u = f*2.0f + LO;
  u = fmaxf(LO, u);
  return 1.41421356f * erfinv_f32(u);
}

__device__ inline float gelu_tanh(float x){
  float x3 = x*x*x;
  float g = 0.7978845608f*(x + 0.044715f*x3);
  float e = __expf(-2.0f*fabsf(g));
  float t = (1.0f - e)/(1.0f + e);
  t = copysignf(t, g);
  return 0.5f*x*(1.0f + t);
}

/* f32 -> bf16 RNE */
__device__ inline ush f2bf(float f){
  unsigned u = __float_as_uint(f);
  unsigned r = (u + 0x7FFFu + ((u>>16)&1u)) >> 16;
  return (ush)r;
}

__device__ inline float blockReduceSum256(float v, volatile float* red){
  for (int o=32;o>0;o>>=1) v += __shfl_down(v, o, 64);
  int w = threadIdx.x>>6, lane = threadIdx.x&63;
  __syncthreads();
  if (lane==0) red[w]=v;
  __syncthreads();
  return red[0]+red[1]+red[2]+red[3];
}

/* ---------------- Kernel A: per-row features ---------------- */
__global__ __launch_bounds__(256) void feat_kernel(
    const float* __restrict__ pt, const float* __restrict__ ptf,
    const float* __restrict__ ftf, float* __restrict__ ws)
{
  const int b = blockIdx.x;
  const int tid = threadIdx.x;
  __shared__ float seg[343];       /* pt[b][169..511]; ctx[t]=seg[7+t] */
  __shared__ float dbuf[CTXN];
  __shared__ float rbuf[CTXN];
  __shared__ float red[4];
  __shared__ float med[2];

  for (int i = tid; i < 343; i += 256) seg[i] = pt[(size_t)b*TPAST + 169 + i];
  if (tid < 2) med[tid] = 0.f;
  __syncthreads();

  for (int t = tid; t < CTXN; t += 256) {
    float v = seg[7+t];
    int clt=0, ceq=0;
    for (int s2=0;s2<CTXN;s2++){ float w = seg[7+s2]; clt += (w < v); ceq += (w == v); }
    if (clt <= 167 && 167 < clt+ceq) med[0] = v;
    if (clt <= 168 && 168 < clt+ceq) med[1] = v;
  }
  __syncthreads();
  float loc = 0.5f*(med[0]+med[1]);

  float part = 0.f;
  for (int t=tid;t<CTXN;t+=256) part += fabsf(seg[7+t]-loc);
  part = blockReduceSum256(part, red);
  float scale = fmaxf(part/(float)CTXN, 1e-6f);

  float pd = 0.f;
  for (int t=tid;t<CTXN;t+=256){
    float d = (t==0)?0.f:(seg[7+t]-seg[6+t]);
    dbuf[t]=d; pd += fabsf(d);
  }
  pd = blockReduceSum256(pd, red);
  float dden = fmaxf(pd/(float)CTXN, 1e-6f);

  float pr = 0.f;
  for (int t=tid;t<CTXN;t+=256){
    int a = t-4; if (a<0) a=0;
    int n = t+1-a;
    float s=0.f, s2s=0.f;
    for (int jj=a;jj<=t;jj++){ float v=seg[7+jj]; s+=v; s2s+=v*v; }
    float fn = (float)n;
    float var = (s2s - s*s/fn) / fmaxf(fn-1.f, 1.f);
    float r = (t>=2)? sqrtf(fmaxf(var,1e-12f)) : 0.f;
    rbuf[t]=r; pr += r;
  }
  pr = blockReduceSum256(pr, red);
  float rden = fmaxf(pr/(float)CTXN, 1e-6f);
  __syncthreads();

  float* sf = ws + SF_OFF + (size_t)b*SFKP;
  if (tid<2) sf[tid]=1.0f;
  if (tid<SFKP-SFK) sf[SFK+tid]=0.f;
  for (int t=tid;t<CTXN;t+=256){
    #pragma unroll
    for (int c=0;c<8;c++)
      sf[2 + c*CTXN + t] = (seg[7 - c + t] - loc)/scale;
    sf[2+8*CTXN+t] = dbuf[t]/dden;
    sf[2+9*CTXN+t] = rbuf[t]/rden;
    #pragma unroll
    for (int f=0; f<4; f++)
      sf[2 + (10+f)*CTXN + t] = ptf[(size_t)b*TPAST*NTF + (size_t)(176+t)*NTF + f];
  }
  for (int i=tid;i<NTF*PREDN;i+=256){
    int f = i/PREDN, t = i - f*PREDN;
    sf[2+14*CTXN + i] = ftf[(size_t)b*PREDN*NTF + t*NTF + f];
  }
  if (tid==0){ ws[LS_OFF + b] = loc; ws[LS_OFF + BATCH + b] = scale; }
}

/* ---------------- Kernel B: LDS-tiled split-K base GEMM ---------------- */
__global__ __launch_bounds__(256) void base_partial_kernel(
    const float* __restrict__ W1, const float* __restrict__ sf, float* __restrict__ partb)
{
  __shared__ float sfT[32][32];
  __shared__ float wT[32][HID];
  const int tid  = threadIdx.x;
  const int rowg = tid >> 5;
  const int colg = tid & 31;
  const int r0 = rowg*4, c0 = colg*4;
  const int rb = blockIdx.x*32;
  const int kc = blockIdx.y;
  const int kbeg = kc*KCH;
  const int kend = (kc==KC-1) ? SFKP : (kbeg+KCH);

  float acc[4][4];
  #pragma unroll
  for (int i=0;i<4;i++)
    #pragma unroll
    for (int j=0;j<4;j++) acc[i][j]=0.f;

  const int sr  = tid >> 3;
  const int sk4 = (tid & 7) * 4;

  for (int kk0 = kbeg; kk0 < kend; kk0 += 32) {
    float4 v = *(const float4*)(sf + (size_t)(rb + sr)*SFKP + kk0 + sk4);
    sfT[sk4+0][sr] = v.x; sfT[sk4+1][sr] = v.y;
    sfT[sk4+2][sr] = v.z; sfT[sk4+3][sr] = v.w;
    #pragma unroll
    for (int p = 0; p < 4; p++) {
      int idx = p*256 + tid;
      int kk = idx >> 5;
      int h4 = (idx & 31) * 4;
      int row = 30 + kk0 + kk; if (row > 4855) row = 4855;
      *(float4*)&wT[kk][h4] = *(const float4*)(W1 + (size_t)row*HID + h4);
    }
    __syncthreads();
    #pragma unroll
    for (int kk = 0; kk < 32; kk++) {
      float4 a = *(const float4*)&sfT[kk][r0];
      float4 b = *(const float4*)&wT[kk][c0];
      acc[0][0]=fmaf(a.x,b.x,acc[0][0]); acc[0][1]=fmaf(a.x,b.y,acc[0][1]);
      acc[0][2]=fmaf(a.x,b.z,acc[0][2]); acc[0][3]=fmaf(a.x,b.w,acc[0][3]);
      acc[1][0]=fmaf(a.y,b.x,acc[1][0]); acc[1][1]=fmaf(a.y,b.y,acc[1][1]);
      acc[1][2]=fmaf(a.y,b.z,acc[1][2]); acc[1][3]=fmaf(a.y,b.w,acc[1][3]);
      acc[2][0]=fmaf(a.z,b.x,acc[2][0]); acc[2][1]=fmaf(a.z,b.y,acc[2][1]);
      acc[2][2]=fmaf(a.z,b.z,acc[2][2]); acc[2][3]=fmaf(a.z,b.w,acc[2][3]);
      acc[3][0]=fmaf(a.w,b.x,acc[3][0]); acc[3][1]=fmaf(a.w,b.y,acc[3][1]);
      acc[3][2]=fmaf(a.w,b.z,acc[3][2]); acc[3][3]=fmaf(a.w,b.w,acc[3][3]);
    }
    __syncthreads();
  }

  float* p = partb + (size_t)kc*BATCH*HID + (size_t)(rb + r0)*HID + c0;
  #pragma unroll
  for (int i=0;i<4;i++){
    float4 o; o.x=acc[i][0]; o.y=acc[i][1]; o.z=acc[i][2]; o.w=acc[i][3];
    *(float4*)(p + (size_t)i*HID) = o;
  }
}

__global__ __launch_bounds__(256) void base_reduce_kernel(
    const float* __restrict__ partb, const float* __restrict__ b1, float* __restrict__ base)
{
  int i = blockIdx.x*256 + threadIdx.x;
  int h = i & 127;
  float s = b1[h];
  #pragma unroll
  for (int kc=0;kc<KC;kc++) s += partb[(size_t)kc*BATCH*HID + i];
  base[i] = s;
}

/* ---------------- prep: bf16 weight repack (B-fragment col-major) ---------------- */
__global__ __launch_bounds__(256) void prep_kernel(
    const float* __restrict__ W1, const float* __restrict__ W2,
    const float* __restrict__ W3, float* __restrict__ ws)
{
  ush* wb = (ush*)(ws + WPREP_OFF);
  int tid = blockIdx.x*256 + threadIdx.x;   /* grid 16*256 = 4096 */
  { int col = tid>>5, k = tid&31;
    wb[tid] = (k<30) ? f2bf(W1[(size_t)k*HID + col]) : (ush)0; }
  #pragma unroll
  for (int j=0;j<4;j++){
    int i = j*4096 + tid;
    int col = i>>7, k = i&127;
    wb[4096 + i] = f2bf(W2[(size_t)k*HID + col]);
  }
  { int col = tid>>7, k = tid&127;
    wb[20480 + tid] = (col<30) ? f2bf(W3[(size_t)k*PREDN + col]) : (ush)0; }
}

/* ---------------- Kernel D: 100-sample MLP via MFMA ---------------- */
__global__ __launch_bounds__(256) void mlp_kernel(
    const float* __restrict__ ws, const float* __restrict__ b2v,
    const float* __restrict__ b3v, float* __restrict__ out)
{
  const int s  = blockIdx.y;
  const int r0 = blockIdx.x*32;
  const int tid = threadIdx.x;
  const int wave = tid>>6, l = tid&63;
  const int wr = wave&1, wc = wave>>1;       /* 2x2 wave grid */
  const int li = l&15, lk = l>>4;            /* lk in 0..3 */

  const float* base = ws + BASE_OFF;
  const ush* wb = (const ush*)(ws + WPREP_OFF);

  __shared__ __attribute__((aligned(16))) ush zb[1024];     /* [32][32] bf16, swz (r&3)<<4 */
  __shared__ float zf[960];                                  /* [32][30] f32 */
  __shared__ __attribute__((aligned(16))) ush h1b[4096];     /* [32][128] bf16, swz (r&7)<<4 */
  __shared__ __attribute__((aligned(16))) ush h2b[4096];

  /* z generation: f32 copy + swizzled bf16 copy; zero bf16 pad cols 30,31 */
  if (tid < 64){
    int r = tid>>1, t = 30 + (tid&1);
    zb[(r*64 + ((t*2) ^ ((r&3)<<4))) >> 1] = 0;
  }
  for (int i=tid; i<960; i+=256){
    int r = i/30, t = i - r*30;
    float z = jax_normal((unsigned)(s*30720 + (r0+r)*30 + t));
    zf[i] = z;
    zb[(r*64 + ((t*2) ^ ((r&3)<<4))) >> 1] = f2bf(z);
  }

  /* init acc with base rows; load W1z B-frags */
  const int row4 = wr*16 + lk*4;             /* local rows row4..row4+3 */
  f32x4 acc[4];
  #pragma unroll
  for (int ct=0; ct<4; ct++){
    int col = wc*64 + ct*16 + li;
    #pragma unroll
    for (int q=0;q<4;q++)
      acc[ct][q] = base[(size_t)(r0+row4+q)*HID + col];
  }
  bf16x8 bw1[4];
  #pragma unroll
  for (int ct=0; ct<4; ct++){
    int col = wc*64 + ct*16 + li;
    bw1[ct] = *(const bf16x8*)&wb[col*32 + lk*8];
  }
  __syncthreads();

  /* W1z stage: A = z tile (K=32) */
  const int arow = wr*16 + li;
  bf16x8 az = *(const bf16x8*)&zb[(arow*64 + ((lk*16) ^ ((arow&3)<<4))) >> 1];
  #pragma unroll
  for (int ct=0; ct<4; ct++)
    acc[ct] = __builtin_amdgcn_mfma_f32_16x16x32_bf16(az, bw1[ct], acc[ct], 0, 0, 0);

  /* gelu -> h1b */
  #pragma unroll
  for (int ct=0; ct<4; ct++){
    int col = wc*64 + ct*16 + li;
    #pragma unroll
    for (int q=0;q<4;q++){
      int r = row4 + q;
      h1b[(r*256 + ((col*2) ^ ((r&7)<<4))) >> 1] = f2bf(gelu_tanh(acc[ct][q]));
    }
  }
  __syncthreads();

  /* W2 stage: K=128 */
  f32x4 acc2[4];
  #pragma unroll
  for (int ct=0; ct<4; ct++){
    float bb = b2v[wc*64 + ct*16 + li];
    acc2[ct][0]=bb; acc2[ct][1]=bb; acc2[ct][2]=bb; acc2[ct][3]=bb;
  }
  bf16x8 a2[4];
  #pragma unroll
  for (int ks=0; ks<4; ks++)
    a2[ks] = *(const bf16x8*)&h1b[(arow*256 + (((ks*64 + lk*16)) ^ ((arow&7)<<4))) >> 1];
  #pragma unroll
  for (int ct=0; ct<4; ct++){
    const ush* wcol = &wb[4096 + (wc*64 + ct*16 + li)*128];
    #pragma unroll
    for (int ks=0; ks<4; ks++){
      bf16x8 bfrag = *(const bf16x8*)&wcol[ks*32 + lk*8];
      acc2[ct] = __builtin_amdgcn_mfma_f32_16x16x32_bf16(a2[ks], bfrag, acc2[ct], 0, 0, 0);
    }
  }
  #pragma unroll
  for (int ct=0; ct<4; ct++){
    int col = wc*64 + ct*16 + li;
    #pragma unroll
    for (int q=0;q<4;q++){
      int r = row4 + q;
      h2b[(r*256 + ((col*2) ^ ((r&7)<<4))) >> 1] = f2bf(gelu_tanh(acc2[ct][q]));
    }
  }
  __syncthreads();

  /* W3 stage: per wave one 16x16 tile; cols wc*16.. (pad >=30) */
  const int col3 = wc*16 + li;
  f32x4 acc3;
  { float bb = (col3 < 30) ? b3v[col3] : 0.f;
    acc3[0]=bb; acc3[1]=bb; acc3[2]=bb; acc3[3]=bb; }
  #pragma unroll
  for (int ks=0; ks<4; ks++){
    bf16x8 a3 = *(const bf16x8*)&h2b[(arow*256 + (((ks*64 + lk*16)) ^ ((arow&7)<<4))) >> 1];
    bf16x8 b3f = *(const bf16x8*)&wb[20480 + col3*128 + ks*32 + lk*8];
    acc3 = __builtin_amdgcn_mfma_f32_16x16x32_bf16(a3, b3f, acc3, 0, 0, 0);
  }
  if (col3 < 30){
    #pragma unroll
    for (int q=0;q<4;q++){
      int r = row4 + q;
      int gb = r0 + r;
      float loc = ws[LS_OFF + gb];
      float scl = ws[LS_OFF + BATCH + gb];
      out[(size_t)gb*(NSAMP*PREDN) + s*PREDN + col3] = (zf[r*30 + col3] - acc3[q])*scl + loc;
    }
  }
}

extern "C" void kernel_launch(void* const* d_in, const int* in_sizes, int n_in,
                              void* d_out, int out_size, void* d_ws, size_t ws_size,
                              hipStream_t stream) {
  (void)in_sizes; (void)n_in; (void)out_size; (void)ws_size;
  const float* pt  = (const float*)d_in[0];
  const float* ptf = (const float*)d_in[2];
  const float* ftf = (const float*)d_in[3];
  const float* W1  = (const float*)d_in[4];
  const float* b1  = (const float*)d_in[5];
  const float* W2  = (const float*)d_in[6];
  const float* b2  = (const float*)d_in[7];
  const float* W3  = (const float*)d_in[8];
  const float* b3  = (const float*)d_in[9];
  float* out = (float*)d_out;
  float* ws  = (float*)d_ws;

  hipLaunchKernelGGL(feat_kernel, dim3(BATCH), dim3(256), 0, stream, pt, ptf, ftf, ws);
  hipLaunchKernelGGL(prep_kernel, dim3(16), dim3(256), 0, stream, W1, W2, W3, ws);
  hipLaunchKernelGGL(base_partial_kernel, dim3(BATCH/32, KC), dim3(256), 0, stream,
                     W1, ws + SF_OFF, ws + PART_OFF);
  hipLaunchKernelGGL(base_reduce_kernel, dim3(BATCH*HID/256), dim3(256), 0, stream,
                     ws + PART_OFF, b1, ws + BASE_OFF);
  hipLaunchKernelGGL(mlp_kernel, dim3(BATCH/32, NSAMP), dim3(256), 0, stream,
                     ws, b2, b3, out);
}

// Round 4
// 97.959 us; speedup vs baseline: 3.5363x; 1.1952x over previous
//
#include <hip/hip_runtime.h>
#include <math.h>

#define CTXN 336
#define PREDN 30
#define NSAMP 100
#define BATCH 1024
#define TPAST 512
#define HID 128
#define NTF 4
#define SFK 4826          /* th(2) + 14*336 + 120 : maps to W1 rows 30..4855 */
#define SFKP 4832         /* padded to multiple of 32; pad region zeroed */
#define KC 8
#define KCH 608           /* 7 chunks of 608 + last 576 */

/* ---- ws layout in BYTES ---- */
#define SFB_OFF   0u                         /* ush  [1024][4832]  9,895,936 B */
#define W1T_OFF   9895936u                   /* ush  [128][4832]   1,236,992 B */
#define LS_OFF_B  11132928u                  /* f32  loc[1024], scale[1024]   */
#define PART_OFF_B 11141120u                 /* f32  [8][1024][128] 4,194,304 */
#define BASE_OFF_B 15335424u                 /* f32  [1024][128]   524,288    */
#define WPK_OFF_B  15859712u                 /* ush  24576 (w1z/w2/w3 packs)  */

typedef unsigned short ush;
typedef __attribute__((ext_vector_type(8))) short bf16x8;
typedef __attribute__((ext_vector_type(4))) float f32x4;

__device__ inline unsigned rotl32(unsigned x, unsigned d){ return (x<<d)|(x>>(32u-d)); }

__device__ inline void tf2x32(unsigned k0, unsigned k1, unsigned x0, unsigned x1,
                              unsigned &o0, unsigned &o1){
  unsigned k2 = k0 ^ k1 ^ 0x1BD11BDAu;
  x0 += k0; x1 += k1;
  x0+=x1; x1=rotl32(x1,13); x1^=x0;
  x0+=x1; x1=rotl32(x1,15); x1^=x0;
  x0+=x1; x1=rotl32(x1,26); x1^=x0;
  x0+=x1; x1=rotl32(x1, 6); x1^=x0;
  x0+=k1; x1+=k2+1u;
  x0+=x1; x1=rotl32(x1,17); x1^=x0;
  x0+=x1; x1=rotl32(x1,29); x1^=x0;
  x0+=x1; x1=rotl32(x1,16); x1^=x0;
  x0+=x1; x1=rotl32(x1,24); x1^=x0;
  x0+=k2; x1+=k0+2u;
  x0+=x1; x1=rotl32(x1,13); x1^=x0;
  x0+=x1; x1=rotl32(x1,15); x1^=x0;
  x0+=x1; x1=rotl32(x1,26); x1^=x0;
  x0+=x1; x1=rotl32(x1, 6); x1^=x0;
  x0+=k0; x1+=k1+3u;
  x0+=x1; x1=rotl32(x1,17); x1^=x0;
  x0+=x1; x1=rotl32(x1,29); x1^=x0;
  x0+=x1; x1=rotl32(x1,16); x1^=x0;
  x0+=x1; x1=rotl32(x1,24); x1^=x0;
  x0+=k1; x1+=k2+4u;
  x0+=x1; x1=rotl32(x1,13); x1^=x0;
  x0+=x1; x1=rotl32(x1,15); x1^=x0;
  x0+=x1; x1=rotl32(x1,26); x1^=x0;
  x0+=x1; x1=rotl32(x1, 6); x1^=x0;
  x0+=k2; x1+=k0+5u;
  o0=x0; o1=x1;
}

/* XLA ErfInv32 (Giles) polynomial; log1p replaced by hw v_log on (1-x)(1+x)
   (Sterbenz-exact factors near |x|->1), sqrt by hw v_sqrt. */
__device__ inline float erfinv_f32(float x){
  float t1 = (1.0f - x)*(1.0f + x);
  float w = -0.69314718056f * __builtin_amdgcn_logf(t1);
  float p;
  if (w < 5.0f) {
    w -= 2.5f;
    p = 2.81022636e-08f;
    p = fmaf(p, w, 3.43273939e-07f);
    p = fmaf(p, w, -3.5233877e-06f);
    p = fmaf(p, w, -4.39150654e-06f);
    p = fmaf(p, w, 0.00021858087f);
    p = fmaf(p, w, -0.00125372503f);
    p = fmaf(p, w, -0.00417768164f);
    p = fmaf(p, w, 0.246640727f);
    p = fmaf(p, w, 1.50140941f);
  } else {
    w = __builtin_amdgcn_sqrtf(w) - 3.0f;
    p = -0.000200214257f;
    p = fmaf(p, w, 0.000100950558f);
    p = fmaf(p, w, 0.00134934322f);
    p = fmaf(p, w, -0.00367342844f);
    p = fmaf(p, w, 0.00573950773f);
    p = fmaf(p, w, -0.0076224613f);
    p = fmaf(p, w, 0.00943887047f);
    p = fmaf(p, w, 1.00167406f);
    p = fmaf(p, w, 2.83297682f);
  }
  return p*x;
}

/* jax.random.normal element j of flat (100,1024,30), key(42), partitionable */
__device__ inline float jax_normal(unsigned j){
  unsigned o0,o1; tf2x32(0u,42u,0u,j,o0,o1);
  unsigned bits = o0 ^ o1;
  float f = __uint_as_float((bits>>9)|0x3f800000u) - 1.0f;
  const float LO = -0.99999994f;
  float u = f*2.0f + LO;
  u = fmaxf(LO, u);
  return 1.41421356f * erfinv_f32(u);
}

/* gelu(tanh form): x*(1 - rcp(exp2(2.3021142*(x+0.044715x^3)) + 1)); 8 VALU */
__device__ inline float gelu_tanh(float x){
  float x2 = x*x;
  float q  = fmaf(0.044715f*x2, x, x);
  float e  = __builtin_amdgcn_exp2f(2.302114202f * q);
  float r  = __builtin_amdgcn_rcpf(e + 1.0f);
  return fmaf(-x, r, x);
}

/* f32 -> bf16 RNE */
__device__ inline ush f2bf(float f){
  unsigned u = __float_as_uint(f);
  unsigned r = (u + 0x7FFFu + ((u>>16)&1u)) >> 16;
  return (ush)r;
}

__device__ inline float blockReduceSum256(float v, volatile float* red){
  for (int o=32;o>0;o>>=1) v += __shfl_down(v, o, 64);
  int w = threadIdx.x>>6, lane = threadIdx.x&63;
  __syncthreads();
  if (lane==0) red[w]=v;
  __syncthreads();
  return red[0]+red[1]+red[2]+red[3];
}

/* ---------------- Kernel A: per-row features (sf written as bf16) ---------------- */
__global__ __launch_bounds__(256) void feat_kernel(
    const float* __restrict__ pt, const float* __restrict__ ptf,
    const float* __restrict__ ftf, char* __restrict__ wsb)
{
  const int b = blockIdx.x;
  const int tid = threadIdx.x;
  __shared__ float seg[343];       /* pt[b][169..511]; ctx[t]=seg[7+t] */
  __shared__ __attribute__((aligned(8))) float segA[CTXN];  /* ctx copy for pair-compares */
  __shared__ float dbuf[CTXN];
  __shared__ float rbuf[CTXN];
  __shared__ float red[4];
  __shared__ float med[2];

  for (int i = tid; i < 343; i += 256) seg[i] = pt[(size_t)b*TPAST + 169 + i];
  if (tid < 2) med[tid] = 0.f;
  __syncthreads();
  for (int i = tid; i < CTXN; i += 256) segA[i] = seg[7+i];
  __syncthreads();

  /* median: rank-counting, 2 elements per LDS read */
  for (int t = tid; t < CTXN; t += 256) {
    float v = segA[t];
    int clt=0, ceq=0;
    #pragma unroll 4
    for (int s2=0;s2<CTXN/2;s2++){
      float2 pq = *(const float2*)&segA[2*s2];
      clt += (pq.x < v) + (pq.y < v);
      ceq += (pq.x == v) + (pq.y == v);
    }
    if (clt <= 167 && 167 < clt+ceq) med[0] = v;
    if (clt <= 168 && 168 < clt+ceq) med[1] = v;
  }
  __syncthreads();
  float loc = 0.5f*(med[0]+med[1]);

  float part = 0.f;
  for (int t=tid;t<CTXN;t+=256) part += fabsf(segA[t]-loc);
  part = blockReduceSum256(part, red);
  float scale = fmaxf(part/(float)CTXN, 1e-6f);

  float pd = 0.f;
  for (int t=tid;t<CTXN;t+=256){
    float d = (t==0)?0.f:(seg[7+t]-seg[6+t]);
    dbuf[t]=d; pd += fabsf(d);
  }
  pd = blockReduceSum256(pd, red);
  float dden = fmaxf(pd/(float)CTXN, 1e-6f);

  float pr = 0.f;
  for (int t=tid;t<CTXN;t+=256){
    int a = t-4; if (a<0) a=0;
    int n = t+1-a;
    float s=0.f, s2s=0.f;
    for (int jj=a;jj<=t;jj++){ float v=seg[7+jj]; s+=v; s2s+=v*v; }
    float fn = (float)n;
    float var = (s2s - s*s/fn) / fmaxf(fn-1.f, 1.f);
    float r = (t>=2)? sqrtf(fmaxf(var,1e-12f)) : 0.f;
    rbuf[t]=r; pr += r;
  }
  pr = blockReduceSum256(pr, red);
  float rden = fmaxf(pr/(float)CTXN, 1e-6f);
  __syncthreads();

  ush* sf = (ush*)(wsb + SFB_OFF) + (size_t)b*SFKP;
  float* ls = (float*)(wsb + LS_OFF_B);
  if (tid<2) sf[tid] = (ush)0x3F80;           /* bf16(1.0) */
  if (tid<SFKP-SFK) sf[SFK+tid] = 0;          /* zero pad */
  float iscale = 1.0f/scale, iden = 1.0f/dden, irden = 1.0f/rden;
  for (int t=tid;t<CTXN;t+=256){
    #pragma unroll
    for (int c=0;c<8;c++)
      sf[2 + c*CTXN + t] = f2bf((seg[7 - c + t] - loc)*iscale);
    sf[2+8*CTXN+t] = f2bf(dbuf[t]*iden);
    sf[2+9*CTXN+t] = f2bf(rbuf[t]*irden);
    #pragma unroll
    for (int f=0; f<4; f++)
      sf[2 + (10+f)*CTXN + t] = f2bf(ptf[(size_t)b*TPAST*NTF + (size_t)(176+t)*NTF + f]);
  }
  for (int i=tid;i<NTF*PREDN;i+=256){
    int f = i/PREDN, t = i - f*PREDN;
    sf[2+14*CTXN + i] = f2bf(ftf[(size_t)b*PREDN*NTF + t*NTF + f]);
  }
  if (tid==0){ ls[b] = loc; ls[BATCH + b] = scale; }
}

/* ---------------- prep: W1[30:] transposed to col-major bf16 ---------------- */
__global__ __launch_bounds__(256) void prep_w1t_kernel(
    const float* __restrict__ W1, char* __restrict__ wsb)
{
  ush* w1t = (ush*)(wsb + W1T_OFF);
  const int k0 = blockIdx.x*32;                 /* 151 blocks */
  const int col = threadIdx.x >> 1;
  const int kh  = (threadIdx.x & 1)*16;
  ush v[16];
  #pragma unroll
  for (int j=0;j<16;j++){
    int k = k0 + kh + j;
    v[j] = (k < SFK) ? f2bf(W1[(size_t)(30+k)*HID + col]) : (ush)0;
  }
  ush* dst = w1t + (size_t)col*SFKP + k0 + kh;
  *(uint4*)dst       = *(const uint4*)&v[0];
  *(uint4*)(dst + 8) = *(const uint4*)&v[8];
}

/* ---------------- prep: small bf16 packs (w1z / w2 / w3) ---------------- */
__global__ __launch_bounds__(256) void prep_kernel(
    const float* __restrict__ W1, const float* __restrict__ W2,
    const float* __restrict__ W3, char* __restrict__ wsb)
{
  ush* wb = (ush*)(wsb + WPK_OFF_B);
  int tid = blockIdx.x*256 + threadIdx.x;   /* grid 16*256 = 4096 */
  { int col = tid>>5, k = tid&31;
    wb[tid] = (k<30) ? f2bf(W1[(size_t)k*HID + col]) : (ush)0; }
  #pragma unroll
  for (int j=0;j<4;j++){
    int i = j*4096 + tid;
    int col = i>>7, k = i&127;
    wb[4096 + i] = f2bf(W2[(size_t)k*HID + col]);
  }
  { int col = tid>>7, k = tid&127;
    wb[20480 + tid] = (col<30) ? f2bf(W3[(size_t)k*PREDN + col]) : (ush)0; }
}

/* ---------------- Kernel B: MFMA split-K base GEMM, frags direct from global --
   16-row x 128-col blocks, 4 waves each own 32 cols; K chunked by 32. */
__global__ __launch_bounds__(256) void base_partial_kernel(
    const char* __restrict__ wsb, float* __restrict__ partb)
{
  const ush* sfb = (const ush*)(wsb + SFB_OFF);
  const ush* w1t = (const ush*)(wsb + W1T_OFF);
  const int tid = threadIdx.x;
  const int w = tid>>6, l = tid&63;
  const int li = l&15, lk = l>>4;
  const int rb = blockIdx.x*16;
  const int kc = blockIdx.y;
  const int kbeg = kc*KCH;
  const int kend = (kc==KC-1) ? SFKP : (kbeg+KCH);

  f32x4 acc0 = {0.f,0.f,0.f,0.f}, acc1 = {0.f,0.f,0.f,0.f};
  const ush* ap  = sfb + (size_t)(rb + li)*SFKP + lk*8;
  const ush* b0p = w1t + (size_t)(w*32 + li)*SFKP + lk*8;
  const ush* b1p = b0p + (size_t)16*SFKP;

  #pragma unroll 4
  for (int kk0 = kbeg; kk0 < kend; kk0 += 32){
    bf16x8 a  = *(const bf16x8*)(ap  + kk0);
    bf16x8 b0 = *(const bf16x8*)(b0p + kk0);
    bf16x8 b1 = *(const bf16x8*)(b1p + kk0);
    acc0 = __builtin_amdgcn_mfma_f32_16x16x32_bf16(a, b0, acc0, 0, 0, 0);
    acc1 = __builtin_amdgcn_mfma_f32_16x16x32_bf16(a, b1, acc1, 0, 0, 0);
  }
  /* C layout: row = lk*4+q, col = li */
  float* p = partb + ((size_t)kc*BATCH + rb)*HID;
  #pragma unroll
  for (int q=0;q<4;q++){
    p[(lk*4+q)*HID + w*32      + li] = acc0[q];
    p[(lk*4+q)*HID + w*32 + 16 + li] = acc1[q];
  }
}

__global__ __launch_bounds__(256) void base_reduce_kernel(
    const float* __restrict__ partb, const float* __restrict__ b1, float* __restrict__ base)
{
  int i = blockIdx.x*256 + threadIdx.x;
  int h = i & 127;
  float s = b1[h];
  #pragma unroll
  for (int kc=0;kc<KC;kc++) s += partb[(size_t)kc*BATCH*HID + i];
  base[i] = s;
}

/* ---------------- Kernel D: 100-sample MLP via MFMA ---------------- */
__global__ __launch_bounds__(256) void mlp_kernel(
    const char* __restrict__ wsb, const float* __restrict__ b2v,
    const float* __restrict__ b3v, float* __restrict__ out)
{
  const int s  = blockIdx.y;
  const int r0 = blockIdx.x*32;
  const int tid = threadIdx.x;
  const int wave = tid>>6, l = tid&63;
  const int wr = wave&1, wc = wave>>1;       /* 2x2 wave grid */
  const int li = l&15, lk = l>>4;

  const float* base = (const float*)(wsb + BASE_OFF_B);
  const float* ls   = (const float*)(wsb + LS_OFF_B);
  const ush*   wb   = (const ush*)(wsb + WPK_OFF_B);

  __shared__ __attribute__((aligned(16))) ush zb[1024];     /* [32][32] bf16, swz (r&3)<<4 */
  __shared__ float zf[960];                                  /* [32][30] f32 */
  __shared__ __attribute__((aligned(16))) ush hb[4096];      /* [32][128] bf16, swz (r&7)<<4; reused h1->h2 */

  if (tid < 64){
    int r = tid>>1, t = 30 + (tid&1);
    zb[(r*64 + ((t*2) ^ ((r&3)<<4))) >> 1] = 0;
  }
  for (int i=tid; i<960; i+=256){
    int r = i/30, t = i - r*30;
    float z = jax_normal((unsigned)(s*30720 + (r0+r)*30 + t));
    zf[i] = z;
    zb[(r*64 + ((t*2) ^ ((r&3)<<4))) >> 1] = f2bf(z);
  }

  /* init acc with base rows; load W1z B-frags */
  const int row4 = wr*16 + lk*4;
  f32x4 acc[4];
  #pragma unroll
  for (int ct=0; ct<4; ct++){
    int col = wc*64 + ct*16 + li;
    #pragma unroll
    for (int q=0;q<4;q++)
      acc[ct][q] = base[(size_t)(r0+row4+q)*HID + col];
  }
  bf16x8 bw1[4];
  #pragma unroll
  for (int ct=0; ct<4; ct++){
    int col = wc*64 + ct*16 + li;
    bw1[ct] = *(const bf16x8*)&wb[col*32 + lk*8];
  }
  __syncthreads();

  const int arow = wr*16 + li;
  bf16x8 az = *(const bf16x8*)&zb[(arow*64 + ((lk*16) ^ ((arow&3)<<4))) >> 1];
  #pragma unroll
  for (int ct=0; ct<4; ct++)
    acc[ct] = __builtin_amdgcn_mfma_f32_16x16x32_bf16(az, bw1[ct], acc[ct], 0, 0, 0);

  /* gelu -> hb (=h1) */
  #pragma unroll
  for (int ct=0; ct<4; ct++){
    int col = wc*64 + ct*16 + li;
    #pragma unroll
    for (int q=0;q<4;q++){
      int r = row4 + q;
      hb[(r*256 + ((col*2) ^ ((r&7)<<4))) >> 1] = f2bf(gelu_tanh(acc[ct][q]));
    }
  }
  __syncthreads();

  /* W2 stage: K=128; pull h1 A-frags to regs, then reuse hb for h2 */
  f32x4 acc2[4];
  #pragma unroll
  for (int ct=0; ct<4; ct++){
    float bb = b2v[wc*64 + ct*16 + li];
    acc2[ct][0]=bb; acc2[ct][1]=bb; acc2[ct][2]=bb; acc2[ct][3]=bb;
  }
  bf16x8 a2[4];
  #pragma unroll
  for (int ks=0; ks<4; ks++)
    a2[ks] = *(const bf16x8*)&hb[(arow*256 + (((ks*64 + lk*16)) ^ ((arow&7)<<4))) >> 1];
  __syncthreads();                              /* all h1 reads done before overwrite */
  #pragma unroll
  for (int ct=0; ct<4; ct++){
    const ush* wcol = &wb[4096 + (wc*64 + ct*16 + li)*128];
    #pragma unroll
    for (int ks=0; ks<4; ks++){
      bf16x8 bfrag = *(const bf16x8*)&wcol[ks*32 + lk*8];
      acc2[ct] = __builtin_amdgcn_mfma_f32_16x16x32_bf16(a2[ks], bfrag, acc2[ct], 0, 0, 0);
    }
  }
  #pragma unroll
  for (int ct=0; ct<4; ct++){
    int col = wc*64 + ct*16 + li;
    #pragma unroll
    for (int q=0;q<4;q++){
      int r = row4 + q;
      hb[(r*256 + ((col*2) ^ ((r&7)<<4))) >> 1] = f2bf(gelu_tanh(acc2[ct][q]));
    }
  }
  __syncthreads();

  /* W3 stage: per wave one 16x16 tile; cols wc*16.. (pad >=30) */
  const int col3 = wc*16 + li;
  f32x4 acc3;
  { float bb = (col3 < 30) ? b3v[col3] : 0.f;
    acc3[0]=bb; acc3[1]=bb; acc3[2]=bb; acc3[3]=bb; }
  #pragma unroll
  for (int ks=0; ks<4; ks++){
    bf16x8 a3  = *(const bf16x8*)&hb[(arow*256 + (((ks*64 + lk*16)) ^ ((arow&7)<<4))) >> 1];
    bf16x8 b3f = *(const bf16x8*)&wb[20480 + col3*128 + ks*32 + lk*8];
    acc3 = __builtin_amdgcn_mfma_f32_16x16x32_bf16(a3, b3f, acc3, 0, 0, 0);
  }
  if (col3 < 30){
    #pragma unroll
    for (int q=0;q<4;q++){
      int r = row4 + q;
      int gb = r0 + r;
      float loc = ls[gb];
      float scl = ls[BATCH + gb];
      out[(size_t)gb*(NSAMP*PREDN) + s*PREDN + col3] = (zf[r*30 + col3] - acc3[q])*scl + loc;
    }
  }
}

extern "C" void kernel_launch(void* const* d_in, const int* in_sizes, int n_in,
                              void* d_out, int out_size, void* d_ws, size_t ws_size,
                              hipStream_t stream) {
  (void)in_sizes; (void)n_in; (void)out_size; (void)ws_size;
  const float* pt  = (const float*)d_in[0];
  const float* ptf = (const float*)d_in[2];
  const float* ftf = (const float*)d_in[3];
  const float* W1  = (const float*)d_in[4];
  const float* b1  = (const float*)d_in[5];
  const float* W2  = (const float*)d_in[6];
  const float* b2  = (const float*)d_in[7];
  const float* W3  = (const float*)d_in[8];
  const float* b3  = (const float*)d_in[9];
  float* out = (float*)d_out;
  char* wsb  = (char*)d_ws;

  hipLaunchKernelGGL(feat_kernel, dim3(BATCH), dim3(256), 0, stream, pt, ptf, ftf, wsb);
  hipLaunchKernelGGL(prep_w1t_kernel, dim3(151), dim3(256), 0, stream, W1, wsb);
  hipLaunchKernelGGL(prep_kernel, dim3(16), dim3(256), 0, stream, W1, W2, W3, wsb);
  hipLaunchKernelGGL(base_partial_kernel, dim3(BATCH/16, KC), dim3(256), 0, stream,
                     wsb, (float*)(wsb + PART_OFF_B));
  hipLaunchKernelGGL(base_reduce_kernel, dim3(BATCH*HID/256), dim3(256), 0, stream,
                     (const float*)(wsb + PART_OFF_B), b1, (float*)(wsb + BASE_OFF_B));
  hipLaunchKernelGGL(mlp_kernel, dim3(BATCH/32, NSAMP), dim3(256), 0, stream,
                     wsb, b2, b3, out);
}